// Round 9
// baseline (77.589 us; speedup 1.0000x reference)
//
#include <hip/hip_runtime.h>
#include <math.h>

#define NTOT  16384
#define NGR   256
#define KNN   50
#define NBINS 5
#define BIGF  1e10f
#define MAXJ  2   // cnt <= 128. cnt ~ Binom(16384,1/256): mean 64, sd 8 -> P(cnt>128) < 1e-13.

// Single fused kernel: one wave per node i.
// Bounds: batch is sorted and cnt <= 128, so every same-graph j < i lies in
// [i-127, i-1] and every same-graph j > i lies in [i+1, i+127]. Two 64-wide
// window loads per side + ballot/popcount give start/end with no prior
// bounds kernel (saves a dispatch + graph-node gap).
//
// Rank: per-slot 32-bit key = sortable(d2) staged in per-wave LDS; count
// loop reads at wave-uniform addresses (same-address broadcast, conflict-
// free, no VALU->SGPR readlane hazards — round-7 win). Pads/self hold
// sortable(BIG) > every valid key: rank-inert, so trip counts are the
// compile-time constants J*64 (fully unrolled ds_read batches).
//
// Ties (exactly-equal fp32 d2, ~2-3 grid-wide): tie-free <=> valid ranks
// form {0..cnt-2} <=> wave rank-sum == (cnt-1)(cnt-2)/2 (ties give a
// strictly positive deficit). On detect, rerun exact loop with
// (h<my)||(h==my && k<c) — local position k IS the index tie-break.
__global__ __launch_bounds__(256, 8)
void knn_fused(const float* __restrict__ pos,
               const int*   __restrict__ batch,
               float*       __restrict__ out)
{
    __shared__ unsigned int hish[4][128];   // 4 waves x 128 sortable-d2 keys = 2 KB

    const int i    = __builtin_amdgcn_readfirstlane((int)(blockIdx.x * 4 + (threadIdx.x >> 6)));
    const int wv   = threadIdx.x >> 6;
    const int lane = threadIdx.x & 63;

    const int g = batch[i];                 // uniform addr -> s_load

    // window-based bounds (4 independent loads, ~1 chain of latency)
    const int jA = i - 128 + lane;          // [i-128, i-65]
    const int jB = i -  64 + lane;          // [i-64,  i-1 ]
    const int jC = i +   1 + lane;          // [i+1,   i+64]
    const int jD = i +  65 + lane;          // [i+65,  i+128]
    const int bA = batch[max(jA, 0)];
    const int bB = batch[max(jB, 0)];
    const int bC = batch[min(jC, NTOT - 1)];
    const int bD = batch[min(jD, NTOT - 1)];
    const int c_lo = __popcll(__ballot(jA >= 0 && bA == g))
                   + __popcll(__ballot(jB >= 0 && bB == g));
    const int c_hi = __popcll(__ballot(jC < NTOT && bC == g))
                   + __popcll(__ballot(jD < NTOT && bD == g));
    const int start = i - c_lo;
    const int end   = i + 1 + c_hi;
    const int cnt   = end - start;          // >= 1 (contains i)
    const int J     = (cnt + 63) >> 6;      // 1..2

    const float xi = pos[(size_t)i * 3 + 0];   // uniform -> s_load + broadcast
    const float yi = pos[(size_t)i * 3 + 1];
    const float zi = pos[(size_t)i * 3 + 2];
    const float sqi = xi * xi + yi * yi + zi * zi;

    unsigned int hi[MAXJ];
    bool valid[MAXJ];
    #pragma unroll
    for (int j = 0; j < MAXJ; ++j) {
        const int c = j * 64 + lane;
        valid[j] = (j < J) && (c < cnt) && ((start + c) != i);
        float d2 = BIGF;                    // self + out-of-range padding stay BIG
        if (valid[j]) {
            const int idx = start + c;
            const float xj = pos[(size_t)idx * 3 + 0];
            const float yj = pos[(size_t)idx * 3 + 1];
            const float zj = pos[(size_t)idx * 3 + 2];
            const float sqj = xj * xj + yj * yj + zj * zj;
            const float dot = xi * xj + yi * yj + zi * zj;
            d2 = sqi + sqj - 2.0f * dot;    // reference's exact fp32 formula
        }
        const unsigned int b = __float_as_uint(d2);
        hi[j] = ((int)b < 0) ? ~b : (b | 0x80000000u);   // float -> sortable uint
        hish[wv][c] = hi[j];                // both slots written: pads covered
    }
    __syncthreads();                        // key writes visible (uniform barrier)

    // fast rank: u32 lt-count, uniform-address b128 broadcast, compile-time
    // trip count (J*16 uint4 reads, fully unrolled)
    int rank[MAXJ] = {0, 0};
    const uint4* __restrict__ k4 = reinterpret_cast<const uint4*>(&hish[wv][0]);
    if (J == 1) {                           // cnt <= 64: 16 b128 reads
        int ra = 0, rb = 0;
        #pragma unroll
        for (int q = 0; q < 16; q += 2) {
            const uint4 A = k4[q], B = k4[q + 1];
            ra += (A.x < hi[0]) + (A.y < hi[0]) + (A.z < hi[0]) + (A.w < hi[0]);
            rb += (B.x < hi[0]) + (B.y < hi[0]) + (B.z < hi[0]) + (B.w < hi[0]);
        }
        rank[0] = ra + rb;
    } else {                                // cnt <= 128: 32 b128 reads
        int ra0 = 0, rb0 = 0, ra1 = 0, rb1 = 0;
        #pragma unroll
        for (int q = 0; q < 32; q += 2) {
            const uint4 A = k4[q], B = k4[q + 1];
            ra0 += (A.x < hi[0]) + (A.y < hi[0]) + (A.z < hi[0]) + (A.w < hi[0]);
            rb0 += (B.x < hi[0]) + (B.y < hi[0]) + (B.z < hi[0]) + (B.w < hi[0]);
            ra1 += (A.x < hi[1]) + (A.y < hi[1]) + (A.z < hi[1]) + (A.w < hi[1]);
            rb1 += (B.x < hi[1]) + (B.y < hi[1]) + (B.z < hi[1]) + (B.w < hi[1]);
        }
        rank[0] = ra0 + rb0;
        rank[1] = ra1 + rb1;
    }

    // tie detection: wave-sum of valid ranks vs (cnt-1)(cnt-2)/2
    {
        int s = (valid[0] ? rank[0] : 0) + (valid[1] ? rank[1] : 0);
        #pragma unroll
        for (int off = 32; off > 0; off >>= 1) s += __shfl_xor(s, off, 64);
        const int expect = ((cnt - 1) * (cnt - 2)) >> 1;
        if (s != expect) {                  // rare exact-tie path
            #pragma unroll
            for (int j = 0; j < MAXJ; ++j) {
                if (!valid[j]) continue;
                const int c = j * 64 + lane;
                int r = 0;
                for (int k = 0; k < cnt; ++k) {   // uniform LDS broadcast
                    const unsigned int h = hish[wv][k];
                    r += (h < hi[j]) || (h == hi[j] && k < c);
                }
                rank[j] = r;
            }
        }
    }

    float* __restrict__ srcO  = out;
    float* __restrict__ dstO  = out + (size_t)NTOT * KNN;
    float* __restrict__ distO = out + (size_t)2 * NTOT * KNN;
    float* __restrict__ rdfO  = out + (size_t)3 * NTOT * KNN;

    const float centers[NBINS] = {0.0f, 2.5f, 5.0f, 7.5f, 10.0f};
    const float gamma = 0.08f;              // 1/(2*2.5^2)
    const float fi = (float)i;

    #pragma unroll
    for (int j = 0; j < MAXJ; ++j) {
        const int c = j * 64 + lane;
        if (valid[j] && rank[j] < KNN) {
            // reconstruct d2 from the sortable key
            const unsigned int s  = hi[j];
            const unsigned int b  = (s & 0x80000000u) ? (s & 0x7fffffffu) : ~s;
            const float d2 = __uint_as_float(b);
            const size_t e = (size_t)i * KNN + rank[j];
            srcO[e]  = (float)(start + c);
            dstO[e]  = fi;
            const float d = sqrtf(fmaxf(d2, 1e-12f));
            distO[e] = d;
            #pragma unroll
            for (int bb = 0; bb < NBINS; ++bb) {
                const float dd = d - centers[bb];
                rdfO[e * NBINS + bb] = __expf(-gamma * dd * dd);
            }
        }
    }

    // pad slots when fewer than K valid neighbors: ascending invalid indices
    // [0..start) ++ {i} ++ [end..N), dist = sqrt(1e10) = 1e5 exactly, rdf = 0.
    if (cnt <= KNN) {
        const int r = (cnt - 1) + lane;     // KNN < 64: at most one slot per lane
        if (r < KNN) {
            const int m = lane;             // m-th smallest BIG-masked index
            int jj;
            if (m < start)       jj = m;
            else if (m == start) jj = i;
            else                 jj = end + (m - start - 1);
            const size_t e = (size_t)i * KNN + r;
            srcO[e]  = (float)jj;
            dstO[e]  = fi;
            distO[e] = 100000.0f;           // sqrt(1e10) exactly
            #pragma unroll
            for (int bb = 0; bb < NBINS; ++bb)
                rdfO[e * NBINS + bb] = 0.0f;   // exp(-8e8) underflows to 0
        }
    }
}

extern "C" void kernel_launch(void* const* d_in, const int* in_sizes, int n_in,
                              void* d_out, int out_size, void* d_ws, size_t ws_size,
                              hipStream_t stream) {
    const float* pos   = (const float*)d_in[0];
    const int*   batch = (const int*)d_in[1];
    float*       out   = (float*)d_out;

    knn_fused<<<dim3(NTOT / 4), dim3(256), 0, stream>>>(pos, batch, out);
}

// Round 10
// 74.573 us; speedup vs baseline: 1.0405x; 1.0405x over previous
//
#include <hip/hip_runtime.h>
#include <math.h>

#define NTOT  16384
#define NGR   256
#define KNN   50
#define NBINS 5
#define BIGF  1e10f
#define MAXJ  2   // cnt <= 128. cnt ~ Binom(16384,1/256): mean 64, sd 8 -> P(cnt>128) < 1e-13.

// Single fused kernel: one wave per node i. No __syncthreads anywhere:
// each wave's LDS key region is wave-private, and same-wave ds_write ->
// ds_read ordering is guaranteed (single LDS pipe, compiler lgkmcnt).
//
// Bounds: batch sorted, cnt <= 128 -> same-graph indices lie in
// [i-127, i+127]. Four 64-wide window loads + ballot/popcount give
// start/end with no separate bounds kernel.
//
// Rank: 32-bit sortable(d2) keys staged in per-wave LDS; count loop reads
// wave-uniform addresses (same-address broadcast, conflict-free, no
// VALU->SGPR readlane hazards — round-7 win). Pads/self hold sortable(BIG)
// > every valid key (rank-inert); trip count kpad = ceil(cnt/8)*8 avoids
// round-9's J*64 padding waste.
//
// Ties (exactly-equal fp32 d2, ~2-3 grid-wide): tie-free <=> valid ranks
// form {0..cnt-2} <=> wave rank-sum == (cnt-1)(cnt-2)/2 (ties give a
// strictly positive deficit). On detect, rerun exact loop with
// (h<my)||(h==my && k<c) — local position k IS the index tie-break.
__global__ __launch_bounds__(256, 8)
void knn_fused(const float* __restrict__ pos,
               const int*   __restrict__ batch,
               float*       __restrict__ out)
{
    __shared__ unsigned int hish[4][128];   // 4 waves x 128 keys = 2 KB, wave-private slices

    const int i    = __builtin_amdgcn_readfirstlane((int)(blockIdx.x * 4 + (threadIdx.x >> 6)));
    const int wv   = threadIdx.x >> 6;
    const int lane = threadIdx.x & 63;

    const int g = batch[i];                 // uniform addr -> s_load

    // window-based bounds (4 independent loads, one latency chain)
    const int jA = i - 128 + lane;          // [i-128, i-65]
    const int jB = i -  64 + lane;          // [i-64,  i-1 ]
    const int jC = i +   1 + lane;          // [i+1,   i+64]
    const int jD = i +  65 + lane;          // [i+65,  i+128]
    const int bA = batch[max(jA, 0)];
    const int bB = batch[max(jB, 0)];
    const int bC = batch[min(jC, NTOT - 1)];
    const int bD = batch[min(jD, NTOT - 1)];
    const int c_lo = __popcll(__ballot(jA >= 0 && bA == g))
                   + __popcll(__ballot(jB >= 0 && bB == g));
    const int c_hi = __popcll(__ballot(jC < NTOT && bC == g))
                   + __popcll(__ballot(jD < NTOT && bD == g));
    const int start = i - c_lo;
    const int end   = i + 1 + c_hi;
    const int cnt   = end - start;          // >= 1 (contains i)
    const int J     = (cnt + 63) >> 6;      // 1..2

    const float xi = pos[(size_t)i * 3 + 0];   // uniform -> s_load + broadcast
    const float yi = pos[(size_t)i * 3 + 1];
    const float zi = pos[(size_t)i * 3 + 2];
    const float sqi = xi * xi + yi * yi + zi * zi;

    unsigned int hi[MAXJ];
    bool valid[MAXJ];
    #pragma unroll
    for (int j = 0; j < MAXJ; ++j) {
        const int c = j * 64 + lane;
        valid[j] = (j < J) && (c < cnt) && ((start + c) != i);
        float d2 = BIGF;                    // self + out-of-range padding stay BIG
        if (valid[j]) {
            const int idx = start + c;
            const float xj = pos[(size_t)idx * 3 + 0];
            const float yj = pos[(size_t)idx * 3 + 1];
            const float zj = pos[(size_t)idx * 3 + 2];
            const float sqj = xj * xj + yj * yj + zj * zj;
            const float dot = xi * xj + yi * yj + zi * zj;
            d2 = sqi + sqj - 2.0f * dot;    // reference's exact fp32 formula
        }
        const unsigned int b = __float_as_uint(d2);
        hi[j] = ((int)b < 0) ? ~b : (b | 0x80000000u);   // float -> sortable uint
        hish[wv][c] = hi[j];                // wave-private: no barrier needed
    }
    // NO __syncthreads: same-wave LDS write->read is ordered by the LDS pipe;
    // compiler inserts the lgkmcnt wait (same-object alias).

    // fast rank: u32 lt-count, uniform-address b128 broadcast (4 keys/read),
    // runtime trip kpad (pads BIG: inert) — no J*64 padding waste.
    int rank[MAXJ] = {0, 0};
    const int kpad = (cnt + 7) & ~7;
    const uint4* __restrict__ k4 = reinterpret_cast<const uint4*>(&hish[wv][0]);
    if (J == 1) {                           // cnt <= 64: half the VALU
        int ra = 0, rb = 0;
        for (int c0 = 0; c0 < kpad; c0 += 8) {
            const uint4 A = k4[(c0 >> 2) + 0];
            const uint4 B = k4[(c0 >> 2) + 1];
            ra += (A.x < hi[0]) + (A.y < hi[0]) + (A.z < hi[0]) + (A.w < hi[0]);
            rb += (B.x < hi[0]) + (B.y < hi[0]) + (B.z < hi[0]) + (B.w < hi[0]);
        }
        rank[0] = ra + rb;
    } else {
        int ra0 = 0, rb0 = 0, ra1 = 0, rb1 = 0;
        for (int c0 = 0; c0 < kpad; c0 += 8) {
            const uint4 A = k4[(c0 >> 2) + 0];
            const uint4 B = k4[(c0 >> 2) + 1];
            ra0 += (A.x < hi[0]) + (A.y < hi[0]) + (A.z < hi[0]) + (A.w < hi[0]);
            rb0 += (B.x < hi[0]) + (B.y < hi[0]) + (B.z < hi[0]) + (B.w < hi[0]);
            ra1 += (A.x < hi[1]) + (A.y < hi[1]) + (A.z < hi[1]) + (A.w < hi[1]);
            rb1 += (B.x < hi[1]) + (B.y < hi[1]) + (B.z < hi[1]) + (B.w < hi[1]);
        }
        rank[0] = ra0 + rb0;
        rank[1] = ra1 + rb1;
    }

    // tie detection: wave-sum of valid ranks vs (cnt-1)(cnt-2)/2
    {
        int s = (valid[0] ? rank[0] : 0) + (valid[1] ? rank[1] : 0);
        #pragma unroll
        for (int off = 32; off > 0; off >>= 1) s += __shfl_xor(s, off, 64);
        const int expect = ((cnt - 1) * (cnt - 2)) >> 1;
        if (s != expect) {                  // rare exact-tie path
            #pragma unroll
            for (int j = 0; j < MAXJ; ++j) {
                if (!valid[j]) continue;
                const int c = j * 64 + lane;
                int r = 0;
                for (int k = 0; k < cnt; ++k) {   // uniform LDS broadcast
                    const unsigned int h = hish[wv][k];
                    r += (h < hi[j]) || (h == hi[j] && k < c);
                }
                rank[j] = r;
            }
        }
    }

    float* __restrict__ srcO  = out;
    float* __restrict__ dstO  = out + (size_t)NTOT * KNN;
    float* __restrict__ distO = out + (size_t)2 * NTOT * KNN;
    float* __restrict__ rdfO  = out + (size_t)3 * NTOT * KNN;

    const float centers[NBINS] = {0.0f, 2.5f, 5.0f, 7.5f, 10.0f};
    const float gamma = 0.08f;              // 1/(2*2.5^2)
    const float fi = (float)i;

    #pragma unroll
    for (int j = 0; j < MAXJ; ++j) {
        const int c = j * 64 + lane;
        if (valid[j] && rank[j] < KNN) {
            // reconstruct d2 from the sortable key
            const unsigned int s  = hi[j];
            const unsigned int b  = (s & 0x80000000u) ? (s & 0x7fffffffu) : ~s;
            const float d2 = __uint_as_float(b);
            const size_t e = (size_t)i * KNN + rank[j];
            srcO[e]  = (float)(start + c);
            dstO[e]  = fi;
            const float d = sqrtf(fmaxf(d2, 1e-12f));
            distO[e] = d;
            #pragma unroll
            for (int bb = 0; bb < NBINS; ++bb) {
                const float dd = d - centers[bb];
                rdfO[e * NBINS + bb] = __expf(-gamma * dd * dd);
            }
        }
    }

    // pad slots when fewer than K valid neighbors: ascending invalid indices
    // [0..start) ++ {i} ++ [end..N), dist = sqrt(1e10) = 1e5 exactly, rdf = 0.
    if (cnt <= KNN) {
        const int r = (cnt - 1) + lane;     // KNN < 64: at most one slot per lane
        if (r < KNN) {
            const int m = lane;             // m-th smallest BIG-masked index
            int jj;
            if (m < start)       jj = m;
            else if (m == start) jj = i;
            else                 jj = end + (m - start - 1);
            const size_t e = (size_t)i * KNN + r;
            srcO[e]  = (float)jj;
            dstO[e]  = fi;
            distO[e] = 100000.0f;           // sqrt(1e10) exactly
            #pragma unroll
            for (int bb = 0; bb < NBINS; ++bb)
                rdfO[e * NBINS + bb] = 0.0f;   // exp(-8e8) underflows to 0
        }
    }
}

extern "C" void kernel_launch(void* const* d_in, const int* in_sizes, int n_in,
                              void* d_out, int out_size, void* d_ws, size_t ws_size,
                              hipStream_t stream) {
    const float* pos   = (const float*)d_in[0];
    const int*   batch = (const int*)d_in[1];
    float*       out   = (float*)d_out;

    knn_fused<<<dim3(NTOT / 4), dim3(256), 0, stream>>>(pos, batch, out);
}